// Round 4
// baseline (126770.923 us; speedup 1.0000x reference)
//
#include <hip/hip_runtime.h>
#include <math.h>

static constexpr int Tc = 128, Vc = 97;

// ---- transposed f32 weight tables in ws (offsets in floats) ----
// T_IN [576][512], T_QKV [512][1536], T_O [512][512], T_FF1 [512][2048],
// T_FF2 [2048][512], T_TOK [512][128], T_RW [512][272]
static constexpr size_t T_IN  = 0;                         // [c][j] c<576 j<512
static constexpr size_t T_QKV = T_IN  + (size_t)576*512;   // [c][j] c<512 j<1536
static constexpr size_t T_O   = T_QKV + (size_t)512*1536;  // [e][j] e<512 j<512
static constexpr size_t T_FF1 = T_O   + (size_t)512*512;   // [d][f] d<512 f<2048
static constexpr size_t T_FF2 = T_FF1 + (size_t)512*2048;  // [k][j] k<2048 j<512
static constexpr size_t T_TOK = T_FF2 + (size_t)2048*512;  // [d][v] d<512 v<128(pad)
static constexpr size_t T_RW  = T_TOK + (size_t)512*128;   // [d][j] d<512 j<272(pad): 0..69 read, 70..267 write

__device__ __forceinline__ float softplusf_(float x) { return x > 20.f ? x : log1pf(expf(x)); }
__device__ __forceinline__ float sigmoidf_(float x) { return 1.f / (1.f + expf(-x)); }

__device__ __forceinline__ float wsum(float v) {
#pragma unroll
  for (int o = 1; o < 64; o <<= 1) v += __shfl_xor(v, o);
  return v;
}
__device__ __forceinline__ float wmax(float v) {
#pragma unroll
  for (int o = 1; o < 64; o <<= 1) v = fmaxf(v, __shfl_xor(v, o));
  return v;
}

// fused 2-value block sum over 1024 threads (16 waves)
__device__ __forceinline__ void bsum2(float a, float b, float* redA, float* redB,
                                      float& oa, float& ob) {
  a = wsum(a); b = wsum(b);
  const int wv = threadIdx.x >> 6, ln = threadIdx.x & 63;
  if (ln == 0) { redA[wv] = a; redB[wv] = b; }
  __syncthreads();
  float sa = 0.f, sb = 0.f;
#pragma unroll
  for (int i = 0; i < 16; ++i) { sa += redA[i]; sb += redB[i]; }
  oa = sa; ob = sb;
}

// ---------------- init: transpose all weights (f32) into ws ----------------
__global__ __launch_bounds__(256) void k_init(const float* __restrict__ W_in,
                                              const float* __restrict__ W_qkv,
                                              const float* __restrict__ W_o,
                                              const float* __restrict__ W_ff1,
                                              const float* __restrict__ W_ff2,
                                              const float* __restrict__ W_tok,
                                              const float* __restrict__ W_read,
                                              const float* __restrict__ W_write,
                                              float* __restrict__ ws) {
  const size_t tid = (size_t)blockIdx.x * 256 + threadIdx.x;
  const size_t nth = (size_t)gridDim.x * 256;
  for (size_t i = tid; i < (size_t)576*512; i += nth) {
    size_t c = i >> 9, j = i & 511;
    ws[T_IN + i] = W_in[j * 576 + c];
  }
  for (size_t i = tid; i < (size_t)512*1536; i += nth) {
    size_t c = i / 1536, j = i % 1536;
    ws[T_QKV + i] = W_qkv[j * 512 + c];
  }
  for (size_t i = tid; i < (size_t)512*512; i += nth) {
    size_t e = i >> 9, j = i & 511;
    ws[T_O + i] = W_o[j * 512 + e];
  }
  for (size_t i = tid; i < (size_t)512*2048; i += nth) {
    size_t d = i >> 11, f = i & 2047;
    ws[T_FF1 + i] = W_ff1[f * 512 + d];
  }
  for (size_t i = tid; i < (size_t)2048*512; i += nth) {
    size_t k = i >> 9, j = i & 511;
    ws[T_FF2 + i] = W_ff2[j * 2048 + k];
  }
  for (size_t i = tid; i < (size_t)512*128; i += nth) {
    size_t d = i >> 7, v = i & 127;
    ws[T_TOK + i] = (v < 97) ? W_tok[v * 512 + d] : 0.f;
  }
  for (size_t i = tid; i < (size_t)512*272; i += nth) {
    size_t d = i / 272, j = i % 272;
    float val = 0.f;
    if (j < 70) val = W_read[j * 512 + d];
    else if (j < 268) val = W_write[(j - 70) * 512 + d];
    ws[T_RW + i] = val;
  }
}

// ---------------- persistent per-batch kernel: 1 wg = 1 batch ----------------
__global__ __launch_bounds__(1024) void k_main(
    const int* __restrict__ x, const float* __restrict__ emb,
    const float* __restrict__ b_in, const float* __restrict__ b_qkv,
    const float* __restrict__ b_o,
    const float* __restrict__ ln1g, const float* __restrict__ ln1b,
    const float* __restrict__ b_ff1, const float* __restrict__ b_ff2,
    const float* __restrict__ ln2g, const float* __restrict__ ln2b,
    const float* __restrict__ b_tok,
    const float* __restrict__ b_read, const float* __restrict__ b_write,
    const float* __restrict__ wt, float* __restrict__ dout) {
  const int b = blockIdx.x, tid = threadIdx.x;
  const int wv = tid >> 6, ln = tid & 63;

  __shared__ float mem[128 * 64];            // NTM memory, persistent
  __shared__ float kc[8 * 512], vc[8 * 512]; // KV cache [slot][h*64+e], persistent
  __shared__ float rwv[128], wwv[128], wwn[128];
  __shared__ float rvec[64];
  __shared__ float wide[576];
  __shared__ float xp[512];
  __shared__ float qv[512];
  __shared__ float scores[64], aw[64];
  __shared__ float ctx[512];
  __shared__ float yrow[512], x2[512], orow[512], onorm[512];
  __shared__ float hbuf[2048];
  __shared__ float part[1024];
  __shared__ float p2[544];
  __shared__ float rp[70], wp[198];
  __shared__ float cosR[128], cosW[128];
  __shared__ float redA[16], redB[16];

  // t=0 state
  for (int i = tid; i < 8192; i += 1024) mem[i] = 0.f;
  if (tid < 128) { float v0 = (tid == 0) ? 1.f : 0.f; rwv[tid] = v0; wwv[tid] = v0; }
  __syncthreads();

  for (int t = 0; t < Tc; ++t) {
    // ---- r = rwv . mem ----
    {
      float a = 0.f;
#pragma unroll
      for (int k2 = 0; k2 < 8; ++k2) { int n = wv * 8 + k2; a += rwv[n] * mem[n * 64 + ln]; }
      part[wv * 64 + ln] = a;
    }
    __syncthreads();
    if (tid < 64) {
      float s = 0.f;
#pragma unroll
      for (int p = 0; p < 16; ++p) s += part[p * 64 + tid];
      rvec[tid] = s;
    }
    __syncthreads();
    // ---- wide = [emb[tok], r] ----
    const int tok = x[b * Tc + t];
    for (int i = tid; i < 576; i += 1024)
      wide[i] = (i < 512) ? emb[(size_t)tok * 512 + i] : rvec[i - 512];
    __syncthreads();

    // ---- xp = W_in @ wide + b_in (2 threads/row, coalesced WT) ----
    {
      const int j = tid & 511, hf = tid >> 9;
      const float* __restrict__ col = wt + T_IN + (size_t)hf * 288 * 512 + j;
      const float* __restrict__ vsrc = wide + hf * 288;
      float a = 0.f;
#pragma unroll 8
      for (int c = 0; c < 288; ++c) a += vsrc[c] * col[(size_t)c * 512];
      part[tid] = a;
    }
    __syncthreads();
    if (tid < 512) xp[tid] = part[tid] + part[tid + 512] + b_in[tid];
    __syncthreads();

    // ---- qkv (k,v straight into cache slot) ----
    {
      const int slot = t & 7;
      for (int j = tid; j < 1536; j += 1024) {
        const float* __restrict__ col = wt + T_QKV + j;
        float a = b_qkv[j];
#pragma unroll 8
        for (int c = 0; c < 512; ++c) a += xp[c] * col[(size_t)c * 1536];
        if (j < 512) qv[j] = a;
        else if (j < 1024) kc[slot * 512 + (j - 512)] = a;
        else vc[slot * 512 + (j - 1024)] = a;
      }
    }
    __syncthreads();

    // ---- attention ----
    for (int p = wv; p < 64; p += 16) {
      const int h = p >> 3, j = p & 7, st = t - 7 + j;
      float c = 0.f;
      if (st >= 0) c = qv[h * 64 + ln] * kc[(st & 7) * 512 + h * 64 + ln];
      c = wsum(c);
      if (ln == 0) scores[p] = (st >= 0) ? c * 0.125f : -INFINITY;
    }
    __syncthreads();
    if (tid < 8) {
      float mx = -INFINITY;
#pragma unroll
      for (int j = 0; j < 8; ++j) mx = fmaxf(mx, scores[tid * 8 + j]);
      float e[8], s = 0.f;
#pragma unroll
      for (int j = 0; j < 8; ++j) { e[j] = expf(scores[tid * 8 + j] - mx); s += e[j]; }
      float inv = 1.f / s;
#pragma unroll
      for (int j = 0; j < 8; ++j) aw[tid * 8 + j] = e[j] * inv;
    }
    __syncthreads();
    if (tid < 512) {
      const int h = tid >> 6;
      float a = 0.f;
#pragma unroll
      for (int j = 0; j < 8; ++j) {
        int st = t - 7 + j;
        if (st >= 0) a += aw[h * 8 + j] * vc[(st & 7) * 512 + tid];
      }
      ctx[tid] = a;
    }
    __syncthreads();

    // ---- attn_out = W_o @ ctx; y = xp + attn_out + b_o ----
    {
      const int j = tid & 511, hf = tid >> 9;
      const float* __restrict__ col = wt + T_O + (size_t)hf * 256 * 512 + j;
      const float* __restrict__ vsrc = ctx + hf * 256;
      float a = 0.f;
#pragma unroll 8
      for (int e = 0; e < 256; ++e) a += vsrc[e] * col[(size_t)e * 512];
      part[tid] = a;
    }
    __syncthreads();
    if (tid < 512) yrow[tid] = part[tid] + part[tid + 512] + b_o[tid] + xp[tid];
    __syncthreads();
    // ---- LN1 ----
    {
      float v = (tid < 512) ? yrow[tid] : 0.f;
      float sa, sb; bsum2(v, v * v, redA, redB, sa, sb);
      float mu = sa * (1.f / 512.f);
      float var = sb * (1.f / 512.f) - mu * mu;
      float rstd = rsqrtf(var + 1e-5f);
      if (tid < 512) x2[tid] = (yrow[tid] - mu) * rstd * ln1g[tid] + ln1b[tid];
    }
    __syncthreads();
    // ---- ff1 + exact gelu ----
    for (int f = tid; f < 2048; f += 1024) {
      const float* __restrict__ col = wt + T_FF1 + f;
      float a = b_ff1[f];
#pragma unroll 8
      for (int d = 0; d < 512; ++d) a += x2[d] * col[(size_t)d * 2048];
      hbuf[f] = 0.5f * a * (1.f + erff(a * 0.70710678118654752f));
    }
    __syncthreads();
    // ---- ff2 ----
    {
      const int j = tid & 511, hf = tid >> 9;
      const float* __restrict__ col = wt + T_FF2 + (size_t)hf * 1024 * 512 + j;
      const float* __restrict__ vsrc = hbuf + hf * 1024;
      float a = 0.f;
#pragma unroll 8
      for (int k = 0; k < 1024; ++k) a += vsrc[k] * col[(size_t)k * 512];
      part[tid] = a;
    }
    __syncthreads();
    if (tid < 512) orow[tid] = part[tid] + part[tid + 512] + b_ff2[tid] + x2[tid];
    __syncthreads();
    // ---- LN2 ----
    {
      float v = (tid < 512) ? orow[tid] : 0.f;
      float sa, sb; bsum2(v, v * v, redA, redB, sa, sb);
      float mu = sa * (1.f / 512.f);
      float var = sb * (1.f / 512.f) - mu * mu;
      float rstd = rsqrtf(var + 1e-5f);
      if (tid < 512) onorm[tid] = (orow[tid] - mu) * rstd * ln2g[tid] + ln2b[tid];
    }
    __syncthreads();
    // ---- logits (8-way c-split) + rp/wp (2-way c-split), one phase ----
    {
      const int v = tid & 127, hf = tid >> 7;
      const float* __restrict__ col = wt + T_TOK + (size_t)hf * 64 * 128 + v;
      const float* __restrict__ vsrc = onorm + hf * 64;
      float a = 0.f;
#pragma unroll 8
      for (int d = 0; d < 64; ++d) a += vsrc[d] * col[(size_t)d * 128];
      part[tid] = a;
      const int j = tid & 511, g = tid >> 9;
      if (j < 272) {
        const float* __restrict__ col2 = wt + T_RW + (size_t)g * 256 * 272 + j;
        const float* __restrict__ vsrc2 = onorm + g * 256;
        float a2 = 0.f;
#pragma unroll 8
        for (int d = 0; d < 256; ++d) a2 += vsrc2[d] * col2[(size_t)d * 272];
        p2[g * 272 + j] = a2;
      }
    }
    __syncthreads();
    if (tid < 97) {
      float a = b_tok[tid];
#pragma unroll
      for (int i = 0; i < 8; ++i) a += part[i * 128 + tid];
      dout[((size_t)b * Tc + t) * Vc + tid] = a;
    }
    if (tid < 268) {
      float a = p2[tid] + p2[272 + tid];
      a += (tid < 70) ? b_read[tid] : b_write[tid - 70];
      if (tid < 70) rp[tid] = a; else wp[tid - 70] = a;
    }
    __syncthreads();
    // ---- cosine similarities (8 waves read-key, 8 waves write-key) ----
    {
      const float* key = (wv < 8) ? rp : wp;
      float* cosb = (wv < 8) ? cosR : cosW;
      const int wl = wv & 7;
      float kl = key[ln];
      for (int i = 0; i < 16; ++i) {
        const int n = wl * 16 + i;
        float a = mem[n * 64 + ln];
        float p = a * kl;
        float q = a * a;
#pragma unroll
        for (int o = 1; o < 64; o <<= 1) { p += __shfl_xor(p, o); q += __shfl_xor(q, o); }
        if (ln == 0) cosb[n] = p / (sqrtf(q) + 1e-12f);
      }
    }
    __syncthreads();
    // ---- addressing chains: wave0=read, wave1=write ----
    if (wv < 2) {
      const float* P = wv ? wp : rp;
      const float* cosb = wv ? cosW : cosR;
      float* prevw = wv ? wwv : rwv;
      float kk = P[ln];
      float kn2 = wsum(kk * kk);
      float kinv = 1.f / (sqrtf(kn2) + 1e-12f);
      float beta = softplusf_(P[64]);
      float g = sigmoidf_(P[65]);
      float sh0 = P[66], sh1 = P[67], sh2 = P[68];
      float m3 = fmaxf(sh0, fmaxf(sh1, sh2));
      float es0 = expf(sh0 - m3), es1 = expf(sh1 - m3), es2 = expf(sh2 - m3);
      float i3 = 1.f / (es0 + es1 + es2);
      es0 *= i3; es1 *= i3; es2 *= i3;
      float gp = 1.f + softplusf_(P[69]);
      float v0 = beta * cosb[ln] * kinv, v1 = beta * cosb[64 + ln] * kinv;
      float mx = wmax(fmaxf(v0, v1));
      float e0 = expf(v0 - mx), e1 = expf(v1 - mx);
      float einv = 1.f / wsum(e0 + e1);
      float w0 = g * e0 * einv + (1.f - g) * prevw[ln];
      float w1 = g * e1 * einv + (1.f - g) * prevw[64 + ln];
      float w0m = __shfl(w0, (ln + 63) & 63), w1m = __shfl(w1, (ln + 63) & 63);
      float w0p = __shfl(w0, (ln + 1) & 63),  w1p = __shfl(w1, (ln + 1) & 63);
      float prev0 = (ln == 0)  ? w1m : w0m;
      float next0 = (ln == 63) ? w1p : w0p;
      float prev1 = (ln == 0)  ? w0m : w1m;
      float next1 = (ln == 63) ? w0p : w1p;
      float t0 = es0 * next0 + es1 * w0 + es2 * prev0;
      float t1 = es0 * next1 + es1 * w1 + es2 * prev1;
      float wt0 = powf(t0 + 1e-12f, gp), wt1 = powf(t1 + 1e-12f, gp);
      float winv = 1.f / (wsum(wt0 + wt1) + 1e-12f);
      w0 = wt0 * winv; w1 = wt1 * winv;
      prevw[ln] = w0; prevw[64 + ln] = w1;
      if (wv) { wwn[ln] = w0; wwn[64 + ln] = w1; }
    }
    __syncthreads();
    // ---- memory update ----
    for (int i = tid; i < 8192; i += 1024) {
      const int n = i >> 6, m = i & 63;
      float e = sigmoidf_(wp[70 + m]);
      float a = tanhf(wp[134 + m]);
      float wn = wwn[n];
      mem[i] = mem[i] * (1.f - wn * e) + wn * a;
    }
    __syncthreads();
  }
}

extern "C" void kernel_launch(void* const* d_in, const int* in_sizes, int n_in,
                              void* d_out, int out_size, void* d_ws, size_t ws_size,
                              hipStream_t stream) {
  (void)in_sizes; (void)n_in; (void)out_size; (void)ws_size;
  const int* x = (const int*)d_in[0];
  const float* emb = (const float*)d_in[1];
  const float* W_in = (const float*)d_in[2];
  const float* b_in = (const float*)d_in[3];
  const float* W_qkv = (const float*)d_in[4];
  const float* b_qkv = (const float*)d_in[5];
  const float* W_o = (const float*)d_in[6];
  const float* b_o = (const float*)d_in[7];
  const float* ln1g = (const float*)d_in[8];
  const float* ln1b = (const float*)d_in[9];
  const float* W_ff1 = (const float*)d_in[10];
  const float* b_ff1 = (const float*)d_in[11];
  const float* W_ff2 = (const float*)d_in[12];
  const float* b_ff2 = (const float*)d_in[13];
  const float* ln2g = (const float*)d_in[14];
  const float* ln2b = (const float*)d_in[15];
  const float* W_tok = (const float*)d_in[16];
  const float* b_tok = (const float*)d_in[17];
  const float* W_read = (const float*)d_in[18];
  const float* b_read = (const float*)d_in[19];
  const float* W_write = (const float*)d_in[20];
  const float* b_write = (const float*)d_in[21];
  float* ws = (float*)d_ws;
  float* out = (float*)d_out;

  hipLaunchKernelGGL(k_init, dim3(512), dim3(256), 0, stream,
                     W_in, W_qkv, W_o, W_ff1, W_ff2, W_tok, W_read, W_write, ws);
  hipLaunchKernelGGL(k_main, dim3(32), dim3(1024), 0, stream,
                     x, emb, b_in, b_qkv, b_o, ln1g, ln1b, b_ff1, b_ff2,
                     ln2g, ln2b, b_tok, b_read, b_write, ws, out);
}

// Round 5
// 37844.788 us; speedup vs baseline: 3.3498x; 3.3498x over previous
//
#include <hip/hip_runtime.h>
#include <math.h>

static constexpr int Tc = 128, Vc = 97;

// ---- transposed f32 weight tables in ws (offsets in floats), [c][j], j contiguous ----
static constexpr size_t T_IN  = 0;                         // [576][512]
static constexpr size_t T_QKV = T_IN  + (size_t)576*512;   // [512][1536]
static constexpr size_t T_O   = T_QKV + (size_t)512*1536;  // [512][512]
static constexpr size_t T_FF1 = T_O   + (size_t)512*512;   // [512][2048]
static constexpr size_t T_FF2 = T_FF1 + (size_t)512*2048;  // [2048][512]
static constexpr size_t T_TOK = T_FF2 + (size_t)2048*512;  // [512][128] (v padded to 128)
static constexpr size_t T_RW  = T_TOK + (size_t)512*128;   // [512][272] (0..69 read, 70..267 write, pad 272)

__device__ __forceinline__ float softplusf_(float x) { return x > 20.f ? x : log1pf(expf(x)); }
__device__ __forceinline__ float sigmoidf_(float x) { return 1.f / (1.f + expf(-x)); }

__device__ __forceinline__ float wsum(float v) {
#pragma unroll
  for (int o = 1; o < 64; o <<= 1) v += __shfl_xor(v, o);
  return v;
}
__device__ __forceinline__ float wmax(float v) {
#pragma unroll
  for (int o = 1; o < 64; o <<= 1) v = fmaxf(v, __shfl_xor(v, o));
  return v;
}

// fused 2-value block sum over 1024 threads (16 waves)
__device__ __forceinline__ void bsum2(float a, float b, float* redA, float* redB,
                                      float& oa, float& ob) {
  a = wsum(a); b = wsum(b);
  const int wv = threadIdx.x >> 6, ln = threadIdx.x & 63;
  if (ln == 0) { redA[wv] = a; redB[wv] = b; }
  __syncthreads();
  float sa = 0.f, sb = 0.f;
#pragma unroll
  for (int i = 0; i < 16; ++i) { sa += redA[i]; sb += redB[i]; }
  oa = sa; ob = sb;
}

// split-K float4 matvec body: 4 accumulators, float4 weight loads
#define MV4(ACC0, ACC1, ACC2, ACC3, W4P, VSRC, NC, STRIDE_F4, UNR)                 \
  {                                                                                \
    _Pragma(UNR) for (int c = 0; c < (NC); ++c) {                                  \
      float4 w4 = (W4P)[(size_t)c * (STRIDE_F4)];                                  \
      float vv = (VSRC)[c];                                                        \
      ACC0 += vv * w4.x; ACC1 += vv * w4.y; ACC2 += vv * w4.z; ACC3 += vv * w4.w;  \
    }                                                                              \
  }

// ---------------- init: transpose all weights (f32) into ws ----------------
__global__ __launch_bounds__(256) void k_init(const float* __restrict__ W_in,
                                              const float* __restrict__ W_qkv,
                                              const float* __restrict__ W_o,
                                              const float* __restrict__ W_ff1,
                                              const float* __restrict__ W_ff2,
                                              const float* __restrict__ W_tok,
                                              const float* __restrict__ W_read,
                                              const float* __restrict__ W_write,
                                              float* __restrict__ ws) {
  const size_t tid = (size_t)blockIdx.x * 256 + threadIdx.x;
  const size_t nth = (size_t)gridDim.x * 256;
  for (size_t i = tid; i < (size_t)576*512; i += nth) {
    size_t c = i >> 9, j = i & 511;
    ws[T_IN + i] = W_in[j * 576 + c];
  }
  for (size_t i = tid; i < (size_t)512*1536; i += nth) {
    size_t c = i / 1536, j = i % 1536;
    ws[T_QKV + i] = W_qkv[j * 512 + c];
  }
  for (size_t i = tid; i < (size_t)512*512; i += nth) {
    size_t e = i >> 9, j = i & 511;
    ws[T_O + i] = W_o[j * 512 + e];
  }
  for (size_t i = tid; i < (size_t)512*2048; i += nth) {
    size_t d = i >> 11, f = i & 2047;
    ws[T_FF1 + i] = W_ff1[f * 512 + d];
  }
  for (size_t i = tid; i < (size_t)2048*512; i += nth) {
    size_t k = i >> 9, j = i & 511;
    ws[T_FF2 + i] = W_ff2[j * 2048 + k];
  }
  for (size_t i = tid; i < (size_t)512*128; i += nth) {
    size_t d = i >> 7, v = i & 127;
    ws[T_TOK + i] = (v < 97) ? W_tok[v * 512 + d] : 0.f;
  }
  for (size_t i = tid; i < (size_t)512*272; i += nth) {
    size_t d = i / 272, j = i % 272;
    float val = 0.f;
    if (j < 70) val = W_read[j * 512 + d];
    else if (j < 268) val = W_write[(j - 70) * 512 + d];
    ws[T_RW + i] = val;
  }
}

// ---------------- persistent per-batch kernel: 1 wg = 1 batch ----------------
__global__ __launch_bounds__(1024, 4) void k_main(
    const int* __restrict__ x, const float* __restrict__ emb,
    const float* __restrict__ b_in, const float* __restrict__ b_qkv,
    const float* __restrict__ b_o,
    const float* __restrict__ ln1g, const float* __restrict__ ln1b,
    const float* __restrict__ b_ff1, const float* __restrict__ b_ff2,
    const float* __restrict__ ln2g, const float* __restrict__ ln2b,
    const float* __restrict__ b_tok,
    const float* __restrict__ b_read, const float* __restrict__ b_write,
    const float* __restrict__ wt, float* __restrict__ dout) {
  const int b = blockIdx.x, tid = threadIdx.x;
  const int wv = tid >> 6, ln = tid & 63;

  __shared__ float mem[128 * 64];            // NTM memory, persistent
  __shared__ float kc[8 * 512], vc[8 * 512]; // KV cache [slot][h*64+e], persistent
  __shared__ float rwv[128], wwv[128], wwn[128];
  __shared__ float rvec[64];
  __shared__ float wide[576];
  __shared__ float xp[512];
  __shared__ float qv[512];
  __shared__ float scores[64], aw[64];
  __shared__ float ctx[512];
  __shared__ float yrow[512], x2[512], orow[512], onorm[512];
  __shared__ float hbuf[2048];
  __shared__ __align__(16) float part[4096];
  __shared__ float rp[70], wp[198];
  __shared__ float cosR[128], cosW[128];
  __shared__ float redA[16], redB[16];

  // t=0 state
  for (int i = tid; i < 8192; i += 1024) mem[i] = 0.f;
  if (tid < 128) { float v0 = (tid == 0) ? 1.f : 0.f; rwv[tid] = v0; wwv[tid] = v0; }
  __syncthreads();

  for (int t = 0; t < Tc; ++t) {
    // ---- r = rwv . mem ----
    {
      float a = 0.f;
#pragma unroll
      for (int k2 = 0; k2 < 8; ++k2) { int n = wv * 8 + k2; a += rwv[n] * mem[n * 64 + ln]; }
      part[wv * 64 + ln] = a;
    }
    __syncthreads();
    if (tid < 64) {
      float s = 0.f;
#pragma unroll
      for (int p = 0; p < 16; ++p) s += part[p * 64 + tid];
      rvec[tid] = s;
    }
    __syncthreads();
    // ---- wide = [emb[tok], r] ----
    const int tok = x[b * Tc + t];
    for (int i = tid; i < 576; i += 1024)
      wide[i] = (i < 512) ? emb[(size_t)tok * 512 + i] : rvec[i - 512];
    __syncthreads();

    // ---- xp = W_in @ wide + b_in : 8 K-chunks x 128 col-groups ----
    {
      const int cs = tid >> 7, g = tid & 127;
      const float4* __restrict__ w4p =
          reinterpret_cast<const float4*>(wt + T_IN + (size_t)(cs * 72) * 512) + g;
      const float* __restrict__ vsrc = wide + cs * 72;
      float a0 = 0.f, a1 = 0.f, a2 = 0.f, a3 = 0.f;
      MV4(a0, a1, a2, a3, w4p, vsrc, 72, 128, "unroll 8")
      *reinterpret_cast<float4*>(part + tid * 4) = make_float4(a0, a1, a2, a3);
    }
    __syncthreads();
    if (tid < 512) {
      float a = b_in[tid];
#pragma unroll
      for (int cs = 0; cs < 8; ++cs) a += part[cs * 512 + tid];
      xp[tid] = a;
    }
    __syncthreads();

    // ---- qkv = W_qkv @ xp : 2 K-chunks x 384 col-groups (768 active threads) ----
    if (tid < 768) {
      const int cs = tid / 384, g = tid % 384;
      const float4* __restrict__ w4p =
          reinterpret_cast<const float4*>(wt + T_QKV + (size_t)(cs * 256) * 1536) + g;
      const float* __restrict__ vsrc = xp + cs * 256;
      float a0 = 0.f, a1 = 0.f, a2 = 0.f, a3 = 0.f;
      MV4(a0, a1, a2, a3, w4p, vsrc, 256, 384, "unroll 8")
      *reinterpret_cast<float4*>(part + tid * 4) = make_float4(a0, a1, a2, a3);
    }
    __syncthreads();
    {
      const int slot = t & 7;
      for (int j = tid; j < 1536; j += 1024) {
        float a = part[j] + part[1536 + j] + b_qkv[j];
        if (j < 512) qv[j] = a;
        else if (j < 1024) kc[slot * 512 + (j - 512)] = a;
        else vc[slot * 512 + (j - 1024)] = a;
      }
    }
    __syncthreads();

    // ---- attention ----
    for (int p = wv; p < 64; p += 16) {
      const int h = p >> 3, j = p & 7, st = t - 7 + j;
      float c = 0.f;
      if (st >= 0) c = qv[h * 64 + ln] * kc[(st & 7) * 512 + h * 64 + ln];
      c = wsum(c);
      if (ln == 0) scores[p] = (st >= 0) ? c * 0.125f : -INFINITY;
    }
    __syncthreads();
    if (tid < 8) {
      float mx = -INFINITY;
#pragma unroll
      for (int j = 0; j < 8; ++j) mx = fmaxf(mx, scores[tid * 8 + j]);
      float e[8], s = 0.f;
#pragma unroll
      for (int j = 0; j < 8; ++j) { e[j] = expf(scores[tid * 8 + j] - mx); s += e[j]; }
      float inv = 1.f / s;
#pragma unroll
      for (int j = 0; j < 8; ++j) aw[tid * 8 + j] = e[j] * inv;
    }
    __syncthreads();
    if (tid < 512) {
      const int h = tid >> 6;
      float a = 0.f;
#pragma unroll
      for (int j = 0; j < 8; ++j) {
        int st = t - 7 + j;
        if (st >= 0) a += aw[h * 8 + j] * vc[(st & 7) * 512 + tid];
      }
      ctx[tid] = a;
    }
    __syncthreads();

    // ---- attn_out = W_o @ ctx : 8 x 128 ----
    {
      const int cs = tid >> 7, g = tid & 127;
      const float4* __restrict__ w4p =
          reinterpret_cast<const float4*>(wt + T_O + (size_t)(cs * 64) * 512) + g;
      const float* __restrict__ vsrc = ctx + cs * 64;
      float a0 = 0.f, a1 = 0.f, a2 = 0.f, a3 = 0.f;
      MV4(a0, a1, a2, a3, w4p, vsrc, 64, 128, "unroll 8")
      *reinterpret_cast<float4*>(part + tid * 4) = make_float4(a0, a1, a2, a3);
    }
    __syncthreads();
    if (tid < 512) {
      float a = b_o[tid] + xp[tid];
#pragma unroll
      for (int cs = 0; cs < 8; ++cs) a += part[cs * 512 + tid];
      yrow[tid] = a;
    }
    __syncthreads();
    // ---- LN1 ----
    {
      float v = (tid < 512) ? yrow[tid] : 0.f;
      float sa, sb; bsum2(v, v * v, redA, redB, sa, sb);
      float mu = sa * (1.f / 512.f);
      float var = sb * (1.f / 512.f) - mu * mu;
      float rstd = rsqrtf(var + 1e-5f);
      if (tid < 512) x2[tid] = (yrow[tid] - mu) * rstd * ln1g[tid] + ln1b[tid];
    }
    __syncthreads();
    // ---- ff1 + exact gelu : 2 K-chunks x 512 col-groups ----
    {
      const int cs = tid >> 9, g = tid & 511;
      const float4* __restrict__ w4p =
          reinterpret_cast<const float4*>(wt + T_FF1 + (size_t)(cs * 256) * 2048) + g;
      const float* __restrict__ vsrc = x2 + cs * 256;
      float a0 = 0.f, a1 = 0.f, a2 = 0.f, a3 = 0.f;
      MV4(a0, a1, a2, a3, w4p, vsrc, 256, 512, "unroll 8")
      *reinterpret_cast<float4*>(part + tid * 4) = make_float4(a0, a1, a2, a3);
    }
    __syncthreads();
    for (int j = tid; j < 2048; j += 1024) {
      float a = part[j] + part[2048 + j] + b_ff1[j];
      hbuf[j] = 0.5f * a * (1.f + erff(a * 0.70710678118654752f));
    }
    __syncthreads();
    // ---- ff2 : 8 K-chunks x 128 col-groups ----
    {
      const int cs = tid >> 7, g = tid & 127;
      const float4* __restrict__ w4p =
          reinterpret_cast<const float4*>(wt + T_FF2 + (size_t)(cs * 256) * 512) + g;
      const float* __restrict__ vsrc = hbuf + cs * 256;
      float a0 = 0.f, a1 = 0.f, a2 = 0.f, a3 = 0.f;
      MV4(a0, a1, a2, a3, w4p, vsrc, 256, 128, "unroll 8")
      *reinterpret_cast<float4*>(part + tid * 4) = make_float4(a0, a1, a2, a3);
    }
    __syncthreads();
    if (tid < 512) {
      float a = b_ff2[tid] + x2[tid];
#pragma unroll
      for (int cs = 0; cs < 8; ++cs) a += part[cs * 512 + tid];
      orow[tid] = a;
    }
    __syncthreads();
    // ---- LN2 ----
    {
      float v = (tid < 512) ? orow[tid] : 0.f;
      float sa, sb; bsum2(v, v * v, redA, redB, sa, sb);
      float mu = sa * (1.f / 512.f);
      float var = sb * (1.f / 512.f) - mu * mu;
      float rstd = rsqrtf(var + 1e-5f);
      if (tid < 512) onorm[tid] = (orow[tid] - mu) * rstd * ln2g[tid] + ln2b[tid];
    }
    __syncthreads();
    // ---- logits (tid<512: 16 K-chunks x 32 groups) + rp/wp (tid 512..783: 4 x 68) ----
    if (tid < 512) {
      const int cs = tid >> 5, g = tid & 31;
      const float4* __restrict__ w4p =
          reinterpret_cast<const float4*>(wt + T_TOK + (size_t)(cs * 32) * 128) + g;
      const float* __restrict__ vsrc = onorm + cs * 32;
      float a0 = 0.f, a1 = 0.f, a2 = 0.f, a3 = 0.f;
      MV4(a0, a1, a2, a3, w4p, vsrc, 32, 32, "unroll 8")
      *reinterpret_cast<float4*>(part + tid * 4) = make_float4(a0, a1, a2, a3);
    } else if (tid < 784) {
      const int u = tid - 512;
      const int cs = u / 68, g = u % 68;
      if (u < 272) {
        const float4* __restrict__ w4p =
            reinterpret_cast<const float4*>(wt + T_RW + (size_t)(cs * 128) * 272) + g;
        const float* __restrict__ vsrc = onorm + cs * 128;
        float a0 = 0.f, a1 = 0.f, a2 = 0.f, a3 = 0.f;
        MV4(a0, a1, a2, a3, w4p, vsrc, 128, 68, "unroll 8")
        *reinterpret_cast<float4*>(part + 2048 + u * 4) = make_float4(a0, a1, a2, a3);
      }
    }
    __syncthreads();
    if (tid < 97) {
      float a = b_tok[tid];
#pragma unroll
      for (int cs = 0; cs < 16; ++cs) a += part[cs * 128 + tid];
      dout[((size_t)b * Tc + t) * Vc + tid] = a;
    }
    if (tid < 268) {
      float a = (tid < 70) ? b_read[tid] : b_write[tid - 70];
#pragma unroll
      for (int cs = 0; cs < 4; ++cs) a += part[2048 + cs * 272 + tid];
      if (tid < 70) rp[tid] = a; else wp[tid - 70] = a;
    }
    __syncthreads();
    // ---- cosine similarities (8 waves read-key, 8 waves write-key) ----
    {
      const float* key = (wv < 8) ? rp : wp;
      float* cosb = (wv < 8) ? cosR : cosW;
      const int wl = wv & 7;
      float kl = key[ln];
      for (int i = 0; i < 16; ++i) {
        const int n = wl * 16 + i;
        float a = mem[n * 64 + ln];
        float p = a * kl;
        float q = a * a;
#pragma unroll
        for (int o = 1; o < 64; o <<= 1) { p += __shfl_xor(p, o); q += __shfl_xor(q, o); }
        if (ln == 0) cosb[n] = p / (sqrtf(q) + 1e-12f);
      }
    }
    __syncthreads();
    // ---- addressing chains: wave0=read, wave1=write ----
    if (wv < 2) {
      const float* P = wv ? wp : rp;
      const float* cosb = wv ? cosW : cosR;
      float* prevw = wv ? wwv : rwv;
      float kk = P[ln];
      float kn2 = wsum(kk * kk);
      float kinv = 1.f / (sqrtf(kn2) + 1e-12f);
      float beta = softplusf_(P[64]);
      float g = sigmoidf_(P[65]);
      float sh0 = P[66], sh1 = P[67], sh2 = P[68];
      float m3 = fmaxf(sh0, fmaxf(sh1, sh2));
      float es0 = expf(sh0 - m3), es1 = expf(sh1 - m3), es2 = expf(sh2 - m3);
      float i3 = 1.f / (es0 + es1 + es2);
      es0 *= i3; es1 *= i3; es2 *= i3;
      float gp = 1.f + softplusf_(P[69]);
      float v0 = beta * cosb[ln] * kinv, v1 = beta * cosb[64 + ln] * kinv;
      float mx = wmax(fmaxf(v0, v1));
      float e0 = expf(v0 - mx), e1 = expf(v1 - mx);
      float einv = 1.f / wsum(e0 + e1);
      float w0 = g * e0 * einv + (1.f - g) * prevw[ln];
      float w1 = g * e1 * einv + (1.f - g) * prevw[64 + ln];
      float w0m = __shfl(w0, (ln + 63) & 63), w1m = __shfl(w1, (ln + 63) & 63);
      float w0p = __shfl(w0, (ln + 1) & 63),  w1p = __shfl(w1, (ln + 1) & 63);
      float prev0 = (ln == 0)  ? w1m : w0m;
      float next0 = (ln == 63) ? w1p : w0p;
      float prev1 = (ln == 0)  ? w0m : w1m;
      float next1 = (ln == 63) ? w0p : w1p;
      float t0 = es0 * next0 + es1 * w0 + es2 * prev0;
      float t1 = es0 * next1 + es1 * w1 + es2 * prev1;
      float wt0 = powf(t0 + 1e-12f, gp), wt1 = powf(t1 + 1e-12f, gp);
      float winv = 1.f / (wsum(wt0 + wt1) + 1e-12f);
      w0 = wt0 * winv; w1 = wt1 * winv;
      prevw[ln] = w0; prevw[64 + ln] = w1;
      if (wv) { wwn[ln] = w0; wwn[64 + ln] = w1; }
    }
    __syncthreads();
    // ---- memory update ----
    for (int i = tid; i < 8192; i += 1024) {
      const int n = i >> 6, m = i & 63;
      float e = sigmoidf_(wp[70 + m]);
      float a = tanhf(wp[134 + m]);
      float wn = wwn[n];
      mem[i] = mem[i] * (1.f - wn * e) + wn * a;
    }
    __syncthreads();
  }
}

extern "C" void kernel_launch(void* const* d_in, const int* in_sizes, int n_in,
                              void* d_out, int out_size, void* d_ws, size_t ws_size,
                              hipStream_t stream) {
  (void)in_sizes; (void)n_in; (void)out_size; (void)ws_size;
  const int* x = (const int*)d_in[0];
  const float* emb = (const float*)d_in[1];
  const float* W_in = (const float*)d_in[2];
  const float* b_in = (const float*)d_in[3];
  const float* W_qkv = (const float*)d_in[4];
  const float* b_qkv = (const float*)d_in[5];
  const float* W_o = (const float*)d_in[6];
  const float* b_o = (const float*)d_in[7];
  const float* ln1g = (const float*)d_in[8];
  const float* ln1b = (const float*)d_in[9];
  const float* W_ff1 = (const float*)d_in[10];
  const float* b_ff1 = (const float*)d_in[11];
  const float* W_ff2 = (const float*)d_in[12];
  const float* b_ff2 = (const float*)d_in[13];
  const float* ln2g = (const float*)d_in[14];
  const float* ln2b = (const float*)d_in[15];
  const float* W_tok = (const float*)d_in[16];
  const float* b_tok = (const float*)d_in[17];
  const float* W_read = (const float*)d_in[18];
  const float* b_read = (const float*)d_in[19];
  const float* W_write = (const float*)d_in[20];
  const float* b_write = (const float*)d_in[21];
  float* ws = (float*)d_ws;
  float* out = (float*)d_out;

  hipLaunchKernelGGL(k_init, dim3(512), dim3(256), 0, stream,
                     W_in, W_qkv, W_o, W_ff1, W_ff2, W_tok, W_read, W_write, ws);
  hipLaunchKernelGGL(k_main, dim3(32), dim3(1024), 0, stream,
                     x, emb, b_in, b_qkv, b_o, ln1g, ln1b, b_ff1, b_ff2,
                     ln2g, ln2b, b_tok, b_read, b_write, ws, out);
}

// Round 6
// 5882.907 us; speedup vs baseline: 21.5490x; 6.4330x over previous
//
#include <hip/hip_runtime.h>
#include <math.h>

static constexpr int Tc = 128, Vc = 97;

// ---- transposed f32 weight tables in ws (floats), [c][j], j contiguous ----
static constexpr size_t T_IN  = 0;                          // [576][512]
static constexpr size_t T_QKV = T_IN  + (size_t)576*512;    // [512][1536]
static constexpr size_t T_O   = T_QKV + (size_t)512*1536;   // [512][512]
static constexpr size_t T_FF1 = T_O   + (size_t)512*512;    // [512][2048]
static constexpr size_t T_FF2 = T_FF1 + (size_t)512*2048;   // [2048][512]
static constexpr size_t T_TOK = T_FF2 + (size_t)2048*512;   // [512][128] remapped: col 16*q+i -> vocab 13*q+i
static constexpr size_t T_RW  = T_TOK + (size_t)512*128;    // [512][288] remapped: col 36*q+i -> row 34*q+i
static constexpr size_t ARENA = T_RW  + (size_t)512*288;    // per-team exchange buffers
static constexpr size_t TEAM_STRIDE = 5376;
static constexpr size_t A_XP=0, A_CTX=512, A_Y=1024, A_O=1536, A_RWP=2048,
                        A_COS=2368, A_R=2624, A_H=3136;     // H: 2048, ends 5184
static constexpr size_t FLG = ARENA + (size_t)32*TEAM_STRIDE; // int flags: 32 teams * 8 stages * 8 q * 16

__device__ __forceinline__ float softplusf_(float x) { return x > 20.f ? x : log1pf(expf(x)); }
__device__ __forceinline__ float sigmoidf_(float x) { return 1.f / (1.f + expf(-x)); }

__device__ __forceinline__ float wsum(float v) {
#pragma unroll
  for (int o = 1; o < 64; o <<= 1) v += __shfl_xor(v, o);
  return v;
}
__device__ __forceinline__ float wmax(float v) {
#pragma unroll
  for (int o = 1; o < 64; o <<= 1) v = fmaxf(v, __shfl_xor(v, o));
  return v;
}

// LLC-coherent (system-scope, relaxed) accessors: sc0 sc1 -> bypass L1/L2, hit Infinity Cache
__device__ __forceinline__ void st_llc(float* p, float v) {
  __hip_atomic_store(p, v, __ATOMIC_RELAXED, __HIP_MEMORY_SCOPE_SYSTEM);
}
__device__ __forceinline__ float ld_llc(const float* p) {
  return __hip_atomic_load(p, __ATOMIC_RELAXED, __HIP_MEMORY_SCOPE_SYSTEM);
}
__device__ __forceinline__ void st_flag(int* p, int v) {
  __hip_atomic_store(p, v, __ATOMIC_RELAXED, __HIP_MEMORY_SCOPE_SYSTEM);
}
__device__ __forceinline__ int ld_flag(const int* p) {
  return __hip_atomic_load(p, __ATOMIC_RELAXED, __HIP_MEMORY_SCOPE_SYSTEM);
}

// publish: producers already issued st_llc; drain, barrier, then owner sets epoch flag
#define PUBF(stage)                                                      \
  do {                                                                   \
    asm volatile("s_waitcnt vmcnt(0)" ::: "memory");                     \
    __syncthreads();                                                     \
    if (tid == 0) st_flag(flg + (stage)*128 + sq*16, t + 1);             \
  } while (0)

// wait: all 8 producers' flags >= need
#define WAITF(stage, need)                                               \
  do {                                                                   \
    if (tid == 0) {                                                      \
      for (int q2 = 0; q2 < 8; ++q2) {                                   \
        while (ld_flag(flg + (stage)*128 + q2*16) < (need))              \
          __builtin_amdgcn_s_sleep(1);                                   \
      }                                                                  \
    }                                                                    \
    __syncthreads();                                                     \
    asm volatile("" ::: "memory");                                       \
  } while (0)

// 64-output matvec slice: 32 K-chunks x 16 col-groups(x4), partials -> part[tid*4]
template <int CH, int SF4>
__device__ __forceinline__ void mv64(const float* __restrict__ wbase,
                                     const float* __restrict__ src,
                                     float* part, int tid) {
  const int cs = tid >> 4, g = tid & 15;
  const float4* __restrict__ w4 =
      reinterpret_cast<const float4*>(wbase + (size_t)cs * CH * (SF4 * 4)) + g;
  const float* __restrict__ v = src + cs * CH;
  float a0 = 0.f, a1 = 0.f, a2 = 0.f, a3 = 0.f;
#pragma unroll 8
  for (int c = 0; c < CH; ++c) {
    float4 w = w4[(size_t)c * SF4];
    float vv = v[c];
    a0 += vv * w.x; a1 += vv * w.y; a2 += vv * w.z; a3 += vv * w.w;
  }
  *reinterpret_cast<float4*>(part + tid * 4) = make_float4(a0, a1, a2, a3);
}

// 256-output matvec slice (ff1): 8 K-chunks x 64 col-groups(x4)
__device__ __forceinline__ void mv256(const float* __restrict__ wbase,
                                      const float* __restrict__ src,
                                      float* part, int tid) {
  const int cs = tid >> 6, g = tid & 63;
  const float4* __restrict__ w4 =
      reinterpret_cast<const float4*>(wbase + (size_t)cs * 64 * 2048) + g;
  const float* __restrict__ v = src + cs * 64;
  float a0 = 0.f, a1 = 0.f, a2 = 0.f, a3 = 0.f;
#pragma unroll 8
  for (int c = 0; c < 64; ++c) {
    float4 w = w4[(size_t)c * 512];
    float vv = v[c];
    a0 += vv * w.x; a1 += vv * w.y; a2 += vv * w.z; a3 += vv * w.w;
  }
  *reinterpret_cast<float4*>(part + tid * 4) = make_float4(a0, a1, a2, a3);
}

// ---------------- init: transposes + remaps + flag/arena zero ----------------
__global__ __launch_bounds__(256) void k_init(const float* __restrict__ W_in,
                                              const float* __restrict__ W_qkv,
                                              const float* __restrict__ W_o,
                                              const float* __restrict__ W_ff1,
                                              const float* __restrict__ W_ff2,
                                              const float* __restrict__ W_tok,
                                              const float* __restrict__ W_read,
                                              const float* __restrict__ W_write,
                                              float* __restrict__ ws) {
  const size_t tid = (size_t)blockIdx.x * 256 + threadIdx.x;
  const size_t nth = (size_t)gridDim.x * 256;
  for (size_t i = tid; i < (size_t)576*512; i += nth) {
    size_t c = i >> 9, j = i & 511;
    ws[T_IN + i] = W_in[j * 576 + c];
  }
  for (size_t i = tid; i < (size_t)512*1536; i += nth) {
    size_t c = i / 1536, j = i % 1536;
    ws[T_QKV + i] = W_qkv[j * 512 + c];
  }
  for (size_t i = tid; i < (size_t)512*512; i += nth) {
    size_t e = i >> 9, j = i & 511;
    ws[T_O + i] = W_o[j * 512 + e];
  }
  for (size_t i = tid; i < (size_t)512*2048; i += nth) {
    size_t d = i >> 11, f = i & 2047;
    ws[T_FF1 + i] = W_ff1[f * 512 + d];
  }
  for (size_t i = tid; i < (size_t)2048*512; i += nth) {
    size_t k = i >> 9, j = i & 511;
    ws[T_FF2 + i] = W_ff2[j * 2048 + k];
  }
  for (size_t i = tid; i < (size_t)512*128; i += nth) {
    size_t d = i >> 7, j = i & 127;
    int qq = (int)(j >> 4), i2 = (int)(j & 15);
    int v = qq * 13 + i2;
    ws[T_TOK + i] = (i2 < 13 && v < 97) ? W_tok[(size_t)v * 512 + d] : 0.f;
  }
  for (size_t i = tid; i < (size_t)512*288; i += nth) {
    size_t d = i / 288, j = i % 288;
    int qq = (int)(j / 36), i2 = (int)(j % 36);
    int idx = qq * 34 + i2;
    float val = 0.f;
    if (i2 < 34 && idx < 268)
      val = (idx < 70) ? W_read[(size_t)idx * 512 + d] : W_write[(size_t)(idx - 70) * 512 + d];
    ws[T_RW + i] = val;
  }
  for (size_t i = tid; i < (size_t)32 * TEAM_STRIDE; i += nth) ws[ARENA + i] = 0.f;
  for (size_t i = tid; i < 32768; i += nth) ((int*)(ws + FLG))[i] = 0;
}

// ---------------- team kernel: 8 wgs per batch, wg = b*8 + q ----------------
__global__ __launch_bounds__(512) void k_main(
    const int* __restrict__ x, const float* __restrict__ emb,
    const float* __restrict__ b_in, const float* __restrict__ b_qkv,
    const float* __restrict__ b_o,
    const float* __restrict__ ln1g, const float* __restrict__ ln1b,
    const float* __restrict__ b_ff1, const float* __restrict__ b_ff2,
    const float* __restrict__ ln2g, const float* __restrict__ ln2b,
    const float* __restrict__ b_tok,
    const float* __restrict__ b_read, const float* __restrict__ b_write,
    float* __restrict__ ws, float* __restrict__ dout) {
  const float* __restrict__ wt = ws;
  const int wg = blockIdx.x, tid = threadIdx.x;
  const int sq = wg & 7, b = wg >> 3;      // slice/head id, batch id
  const int wv = tid >> 6, ln = tid & 63;
  float* ar = ws + ARENA + (size_t)b * TEAM_STRIDE;
  int* flg = (int*)(ws + FLG) + b * 1024;

  __shared__ float memS[16 * 64];            // owned NTM memory rows [16q..16q+16)
  __shared__ float kcS[8 * 64], vcS[8 * 64]; // own head's KV cache
  __shared__ float rwvS[128], wwvS[128], wwnS[128];
  __shared__ float rvec[64];
  __shared__ float wideS[576];
  __shared__ float xpS[512];
  __shared__ float qhS[64];
  __shared__ float scoresS[8], awS[8];
  __shared__ float ctxS[512];
  __shared__ float yS[512], x2S[512], oS[512], onS[512];
  __shared__ float hS[2048];
  __shared__ __align__(16) float part[2048];
  __shared__ float rwpS[268];
  __shared__ float cosS[256];                // [0..127]=R, [128..255]=W
  __shared__ float redA[8], redB[8];

  for (int i = tid; i < 1024; i += 512) memS[i] = 0.f;
  if (tid < 128) { float v0 = (tid == 0) ? 1.f : 0.f; rwvS[tid] = v0; wwvS[tid] = v0; }
  __syncthreads();

  for (int t = 0; t < Tc; ++t) {
    // ---- r (partials published at end of previous step) ----
    if (t > 0) {
      WAITF(7, t);
      if (tid < 64) {
        float s = 0.f;
#pragma unroll
        for (int q2 = 0; q2 < 8; ++q2) s += ld_llc(ar + A_R + q2 * 64 + tid);
        rvec[tid] = s;
      }
    } else if (tid < 64) rvec[tid] = 0.f;
    __syncthreads();
    const int tok = x[b * Tc + t];
    for (int i = tid; i < 576; i += 512)
      wideS[i] = (i < 512) ? emb[(size_t)tok * 512 + i] : rvec[i - 512];
    __syncthreads();

    // ---- xp slice ----
    mv64<18, 128>(wt + T_IN + 64 * sq, wideS, part, tid);
    __syncthreads();
    if (tid < 64) {
      float s = 0.f;
#pragma unroll
      for (int cs = 0; cs < 32; ++cs) s += part[cs * 64 + tid];
      st_llc(ar + A_XP + 64 * sq + tid, s + b_in[64 * sq + tid]);
    }
    PUBF(0);
    WAITF(0, t + 1);
    xpS[tid] = ld_llc(ar + A_XP + tid);
    __syncthreads();

    // ---- qkv slice (own head; k,v straight into local cache) ----
    const int slot = t & 7;
    for (int p3 = 0; p3 < 3; ++p3) {
      mv64<16, 384>(wt + T_QKV + p3 * 512 + 64 * sq, xpS, part, tid);
      __syncthreads();
      if (tid < 64) {
        float s = 0.f;
#pragma unroll
        for (int cs = 0; cs < 32; ++cs) s += part[cs * 64 + tid];
        s += b_qkv[p3 * 512 + 64 * sq + tid];
        if (p3 == 0) qhS[tid] = s;
        else if (p3 == 1) kcS[slot * 64 + tid] = s;
        else vcS[slot * 64 + tid] = s;
      }
      __syncthreads();
    }
    // ---- attention for head sq (fully local) ----
    if (wv < 8) {
      int st = t - 7 + wv;
      float c = 0.f;
      if (st >= 0) c = qhS[ln] * kcS[(st & 7) * 64 + ln];
      c = wsum(c);
      if (ln == 0) scoresS[wv] = (st >= 0) ? c * 0.125f : -INFINITY;
    }
    __syncthreads();
    if (tid == 0) {
      float mx = -INFINITY;
      for (int j = 0; j < 8; ++j) mx = fmaxf(mx, scoresS[j]);
      float e[8], ssum = 0.f;
      for (int j = 0; j < 8; ++j) { e[j] = expf(scoresS[j] - mx); ssum += e[j]; }
      float inv = 1.f / ssum;
      for (int j = 0; j < 8; ++j) awS[j] = e[j] * inv;
    }
    __syncthreads();
    if (tid < 64) {
      float a = 0.f;
#pragma unroll
      for (int j = 0; j < 8; ++j) {
        int st = t - 7 + j;
        if (st >= 0) a += awS[j] * vcS[(st & 7) * 64 + tid];
      }
      st_llc(ar + A_CTX + 64 * sq + tid, a);
    }
    PUBF(1);
    WAITF(1, t + 1);
    ctxS[tid] = ld_llc(ar + A_CTX + tid);
    __syncthreads();

    // ---- attn_out slice + residual ----
    mv64<16, 128>(wt + T_O + 64 * sq, ctxS, part, tid);
    __syncthreads();
    if (tid < 64) {
      float s = 0.f;
#pragma unroll
      for (int cs = 0; cs < 32; ++cs) s += part[cs * 64 + tid];
      st_llc(ar + A_Y + 64 * sq + tid, s + b_o[64 * sq + tid] + xpS[64 * sq + tid]);
    }
    PUBF(2);
    WAITF(2, t + 1);
    yS[tid] = ld_llc(ar + A_Y + tid);
    __syncthreads();
    // ---- LN1 (redundant) ----
    {
      float v = yS[tid];
      float a = wsum(v), b2 = wsum(v * v);
      if (ln == 0) { redA[wv] = a; redB[wv] = b2; }
      __syncthreads();
      float sa = 0.f, sb = 0.f;
#pragma unroll
      for (int i2 = 0; i2 < 8; ++i2) { sa += redA[i2]; sb += redB[i2]; }
      float mu = sa * (1.f / 512.f);
      float var = sb * (1.f / 512.f) - mu * mu;
      float rstd = rsqrtf(var + 1e-5f);
      x2S[tid] = (yS[tid] - mu) * rstd * ln1g[tid] + ln1b[tid];
    }
    __syncthreads();

    // ---- ff1 slice + gelu ----
    mv256(wt + T_FF1 + 256 * sq, x2S, part, tid);
    __syncthreads();
    if (tid < 256) {
      float s = 0.f;
#pragma unroll
      for (int cs = 0; cs < 8; ++cs) s += part[cs * 256 + tid];
      s += b_ff1[256 * sq + tid];
      st_llc(ar + A_H + 256 * sq + tid, 0.5f * s * (1.f + erff(s * 0.70710678118654752f)));
    }
    PUBF(3);
    WAITF(3, t + 1);
    for (int i = tid; i < 2048; i += 512) hS[i] = ld_llc(ar + A_H + i);
    __syncthreads();

    // ---- ff2 slice + residual ----
    mv64<64, 128>(wt + T_FF2 + 64 * sq, hS, part, tid);
    __syncthreads();
    if (tid < 64) {
      float s = 0.f;
#pragma unroll
      for (int cs = 0; cs < 32; ++cs) s += part[cs * 64 + tid];
      st_llc(ar + A_O + 64 * sq + tid, s + b_ff2[64 * sq + tid] + x2S[64 * sq + tid]);
    }
    PUBF(4);
    WAITF(4, t + 1);
    oS[tid] = ld_llc(ar + A_O + tid);
    __syncthreads();
    // ---- LN2 (redundant) ----
    {
      float v = oS[tid];
      float a = wsum(v), b2 = wsum(v * v);
      if (ln == 0) { redA[wv] = a; redB[wv] = b2; }
      __syncthreads();
      float sa = 0.f, sb = 0.f;
#pragma unroll
      for (int i2 = 0; i2 < 8; ++i2) { sa += redA[i2]; sb += redB[i2]; }
      float mu = sa * (1.f / 512.f);
      float var = sb * (1.f / 512.f) - mu * mu;
      float rstd = rsqrtf(var + 1e-5f);
      onS[tid] = (oS[tid] - mu) * rstd * ln2g[tid] + ln2b[tid];
    }
    __syncthreads();

    // ---- rp/wp slice ----
    if (tid < 288) {
      const int cs = tid / 9, g = tid % 9;
      const float4* __restrict__ w4 =
          reinterpret_cast<const float4*>(wt + T_RW + (size_t)(cs * 16) * 288 + 36 * sq) + g;
      const float* __restrict__ v = onS + cs * 16;
      float a0 = 0.f, a1 = 0.f, a2 = 0.f, a3 = 0.f;
#pragma unroll
      for (int c = 0; c < 16; ++c) {
        float4 w = w4[(size_t)c * 72];
        float vv = v[c];
        a0 += vv * w.x; a1 += vv * w.y; a2 += vv * w.z; a3 += vv * w.w;
      }
      *reinterpret_cast<float4*>(part + cs * 36 + g * 4) = make_float4(a0, a1, a2, a3);
    }
    __syncthreads();
    if (tid < 34) {
      int idx = 34 * sq + tid;
      if (idx < 268) {
        float s = 0.f;
#pragma unroll
        for (int cs = 0; cs < 32; ++cs) s += part[cs * 36 + tid];
        s += (idx < 70) ? b_read[idx] : b_write[idx - 70];
        st_llc(ar + A_RWP + idx, s);
      }
    }
    PUBF(5);
    // ---- logits slice (overlaps rwp exchange) ----
    if (tid < 128) {
      const int cs = tid >> 2, g = tid & 3;
      const float4* __restrict__ w4 =
          reinterpret_cast<const float4*>(wt + T_TOK + (size_t)(cs * 16) * 128 + 16 * sq) + g;
      const float* __restrict__ v = onS + cs * 16;
      float a0 = 0.f, a1 = 0.f, a2 = 0.f, a3 = 0.f;
#pragma unroll
      for (int c = 0; c < 16; ++c) {
        float4 w = w4[(size_t)c * 32];
        float vv = v[c];
        a0 += vv * w.x; a1 += vv * w.y; a2 += vv * w.z; a3 += vv * w.w;
      }
      *reinterpret_cast<float4*>(part + tid * 4) = make_float4(a0, a1, a2, a3);
    }
    __syncthreads();
    if (tid < 13) {
      int v = 13 * sq + tid;
      if (v < Vc) {
        float s = 0.f;
#pragma unroll
        for (int cs = 0; cs < 32; ++cs) s += part[cs * 16 + tid];
        dout[((size_t)b * Tc + t) * Vc + v] = s + b_tok[v];
      }
    }
    WAITF(5, t + 1);
    if (tid < 268) rwpS[tid] = ld_llc(ar + A_RWP + tid);
    __syncthreads();

    // ---- cosine sim for own 16 memory rows (both keys) ----
    {
#pragma unroll
      for (int p = 0; p < 4; ++p) {
        int j = wv + 8 * p;               // 0..31
        int row = j & 15, ksel = j >> 4;
        const float* key = ksel ? (rwpS + 70) : rwpS;
        float m = memS[row * 64 + ln];
        float pp = m * key[ln], qq = m * m;
#pragma unroll
        for (int o = 1; o < 64; o <<= 1) { pp += __shfl_xor(pp, o); qq += __shfl_xor(qq, o); }
        if (ln == 0) st_llc(ar + A_COS + ksel * 128 + 16 * sq + row, pp / (sqrtf(qq) + 1e-12f));
      }
    }
    PUBF(6);
    WAITF(6, t + 1);
    if (tid < 256) cosS[tid] = ld_llc(ar + A_COS + tid);
    __syncthreads();

    // ---- addressing chains (redundant): wave0=read, wave1=write ----
    if (wv < 2) {
      const float* P = wv ? (rwpS + 70) : rwpS;
      const float* cosb = cosS + wv * 128;
      float* prevw = wv ? wwvS : rwvS;
      float kk = P[ln];
      float kn2 = wsum(kk * kk);
      float kinv = 1.f / (sqrtf(kn2) + 1e-12f);
      float beta = softplusf_(P[64]);
      float g = sigmoidf_(P[65]);
      float sh0 = P[66], sh1 = P[67], sh2 = P[68];
      float m3 = fmaxf(sh0, fmaxf(sh1, sh2));
      float es0 = expf(sh0 - m3), es1 = expf(sh1 - m3), es2 = expf(sh2 - m3);
      float i3 = 1.f / (es0 + es1 + es2);
      es0 *= i3; es1 *= i3; es2 *= i3;
      float gp = 1.f + softplusf_(P[69]);
      float v0 = beta * cosb[ln] * kinv, v1 = beta * cosb[64 + ln] * kinv;
      float mx = wmax(fmaxf(v0, v1));
      float e0 = expf(v0 - mx), e1 = expf(v1 - mx);
      float einv = 1.f / wsum(e0 + e1);
      float w0 = g * e0 * einv + (1.f - g) * prevw[ln];
      float w1 = g * e1 * einv + (1.f - g) * prevw[64 + ln];
      float w0m = __shfl(w0, (ln + 63) & 63), w1m = __shfl(w1, (ln + 63) & 63);
      float w0p = __shfl(w0, (ln + 1) & 63),  w1p = __shfl(w1, (ln + 1) & 63);
      float prev0 = (ln == 0)  ? w1m : w0m;
      float next0 = (ln == 63) ? w1p : w0p;
      float prev1 = (ln == 0)  ? w0m : w1m;
      float next1 = (ln == 63) ? w0p : w1p;
      float t0 = es0 * next0 + es1 * w0 + es2 * prev0;
      float t1 = es0 * next1 + es1 * w1 + es2 * prev1;
      float wt0 = powf(t0 + 1e-12f, gp), wt1 = powf(t1 + 1e-12f, gp);
      float winv = 1.f / (wsum(wt0 + wt1) + 1e-12f);
      w0 = wt0 * winv; w1 = wt1 * winv;
      prevw[ln] = w0; prevw[64 + ln] = w1;
      if (wv) { wwnS[ln] = w0; wwnS[64 + ln] = w1; }
    }
    __syncthreads();
    // ---- memory update (own rows) ----
    for (int i = tid; i < 1024; i += 512) {
      int nl = i >> 6, m = i & 63;
      float e = sigmoidf_(rwpS[140 + m]);   // wp[70+m]
      float a = tanhf(rwpS[204 + m]);       // wp[134+m]
      float wn = wwnS[16 * sq + nl];
      memS[i] = memS[i] * (1.f - wn * e) + wn * a;
    }
    __syncthreads();
    // ---- r partial for next step ----
    if (tid < 64) {
      float s = 0.f;
#pragma unroll
      for (int nl = 0; nl < 16; ++nl) s += rwvS[16 * sq + nl] * memS[nl * 64 + tid];
      st_llc(ar + A_R + 64 * sq + tid, s);
    }
    PUBF(7);
  }
}

extern "C" void kernel_launch(void* const* d_in, const int* in_sizes, int n_in,
                              void* d_out, int out_size, void* d_ws, size_t ws_size,
                              hipStream_t stream) {
  (void)in_sizes; (void)n_in; (void)out_size; (void)ws_size;
  const int* x = (const int*)d_in[0];
  const float* emb = (const float*)d_in[1];
  const float* W_in = (const float*)d_in[2];
  const float* b_in = (const float*)d_in[3];
  const float* W_qkv = (const float*)d_in[4];
  const float* b_qkv = (const float*)d_in[5];
  const float* W_o = (const float*)d_in[6];
  const float* b_o = (const float*)d_in[7];
  const float* ln1g = (const float*)d_in[8];
  const float* ln1b = (const float*)d_in[9];
  const float* W_ff1 = (const float*)d_in[10];
  const float* b_ff1 = (const float*)d_in[11];
  const float* W_ff2 = (const float*)d_in[12];
  const float* b_ff2 = (const float*)d_in[13];
  const float* ln2g = (const float*)d_in[14];
  const float* ln2b = (const float*)d_in[15];
  const float* W_tok = (const float*)d_in[16];
  const float* b_tok = (const float*)d_in[17];
  const float* W_read = (const float*)d_in[18];
  const float* b_read = (const float*)d_in[19];
  const float* W_write = (const float*)d_in[20];
  const float* b_write = (const float*)d_in[21];
  float* ws = (float*)d_ws;
  float* out = (float*)d_out;

  hipLaunchKernelGGL(k_init, dim3(512), dim3(256), 0, stream,
                     W_in, W_qkv, W_o, W_ff1, W_ff2, W_tok, W_read, W_write, ws);
  hipLaunchKernelGGL(k_main, dim3(256), dim3(512), 0, stream,
                     x, emb, b_in, b_qkv, b_o, ln1g, ln1b, b_ff1, b_ff2,
                     ln2g, ln2b, b_tok, b_read, b_write, ws, out);
}